// Round 2
// baseline (269.907 us; speedup 1.0000x reference)
//
#include <hip/hip_runtime.h>
#include <hip/hip_bf16.h>

typedef __hip_bfloat16 bf16;

#define CAP 1024   // max tracked edges with dst==0 (expected ~32 = Binomial(E,1/N))

struct Ws {
    int   count;      // number of edges with dst == 0
    int   is64;      // edge_index width: 1 = int64, 0 = int32
    int   isf32;     // float buffers: 1 = fp32, 0 = bf16
    int   pad[13];
    int   srcs[CAP];  // src node of each dst==0 edge
    int   degs[CAP];  // in-degree (excl. self loop) of each listed src
    float agg[128];   // agg row 0 accumulator
};

// dtype-adaptive float load (wave-uniform branch)
__device__ __forceinline__ float ldf(const void* p, int isf32, int i) {
    if (isf32) return ((const float*)p)[i];
    return __bfloat162float(((const bf16*)p)[i]);
}

__device__ __forceinline__ int load_idx(const void* ei, int is64, long long pos) {
    if (is64) return (int)((const long long*)ei)[pos];
    return ((const int*)ei)[pos];
}

// ---- 1. init + dtype detection -------------------------------------------
__global__ void k_init(Ws* w, const void* ei, const void* wenc) {
    int t = threadIdx.x;
    if (t == 0) {
        w->count = 0;
        // Index width: int64 values < 1e5 -> every high 32-bit word is 0.
        // int32 layout: odd words are random src ids; P(16 all zero) ~ 1e-80.
        const int* e32 = (const int*)ei;
        int is64 = 1;
        for (int i = 0; i < 16; i++)
            if (e32[2 * i + 1] != 0) is64 = 0;
        w->is64 = is64;
        // Float width: probe W_enc (values ~N(0,0.05)). Interpreted as bf16,
        // fp32 data's low-mantissa halves are uniform random 16-bit words ->
        // some have exponent >= 137 (|v| >= 2^10). bf16 data never does.
        const unsigned short* u = (const unsigned short*)wenc;
        int isf32 = 0;
        for (int i = 0; i < 64; i++) {
            unsigned short e = (u[i] >> 7) & 0xFF;
            if (e >= 137) isf32 = 1;
        }
        w->isf32 = isf32;
    }
    for (int i = t; i < CAP; i += blockDim.x) w->degs[i] = 0;
    for (int i = t; i < 128; i += blockDim.x) w->agg[i] = 0.0f;
}

// ---- 2. find all edges with dst == 0 -------------------------------------
__global__ void k_find(const void* ei, int E, Ws* w) {
    int e = threadIdx.x + blockIdx.x * blockDim.x;
    if (e >= E) return;
    int is64 = w->is64;
    int d = load_idx(ei, is64, (long long)E + e);
    if (d == 0) {
        int p = atomicAdd(&w->count, 1);
        if (p < CAP) w->srcs[p] = load_idx(ei, is64, e);
    }
}

// ---- 3. in-degree of each listed src (small-set histogram) ---------------
__global__ void k_deg(const void* ei, int E, Ws* w) {
    __shared__ int ss[CAP];
    int cnt = min(w->count, CAP);
    for (int i = threadIdx.x; i < cnt; i += blockDim.x) ss[i] = w->srcs[i];
    __syncthreads();
    int e = threadIdx.x + blockIdx.x * blockDim.x;
    if (e >= E) return;
    int d = load_idx(ei, w->is64, (long long)E + e);
    for (int j = 0; j < cnt; j++)
        if (d == ss[j]) atomicAdd(&w->degs[j], 1);
}

// ---- 4. encoder + GCN matvec for the ~33 relevant nodes ------------------
// one block (128 threads) per work item; item i==cnt is the (0,0) self loop
__global__ void k_gather(const void* __restrict__ nf,
                         const void* __restrict__ Wenc,
                         const void* __restrict__ benc,
                         const void* __restrict__ Wgcn,
                         Ws* w) {
    __shared__ float enc[128];
    int isf32 = w->isf32;
    int cnt  = min(w->count, CAP);
    int deg0 = w->count + 1;           // self loop included
    int t = threadIdx.x;               // 0..127
    for (int i = blockIdx.x; i <= cnt; i += gridDim.x) {
        int s; float norm;
        if (i < cnt) {
            s = w->srcs[i];
            norm = rsqrtf((float)(w->degs[i] + 1)) * rsqrtf((float)deg0);
        } else {                        // self loop (0,0)
            s = 0;
            norm = 1.0f / (float)deg0;
        }
        // enc[t] = relu(W_enc[t,:] . nf[s,:] + b_enc[t])
        long long nbase = (long long)s * 64;
        long long wbase = (long long)t * 64;
        float acc = 0.0f;
        for (int k = 0; k < 64; k++)
            acc += ldf(Wenc, isf32, wbase + k) * ldf(nf, isf32, nbase + k);
        acc += ldf(benc, isf32, t);
        enc[t] = fmaxf(acc, 0.0f);
        __syncthreads();
        // xw[t] = W_gcn[t,:] . enc
        long long gbase = (long long)t * 128;
        float acc2 = 0.0f;
        for (int k = 0; k < 128; k++)
            acc2 += ldf(Wgcn, isf32, gbase + k) * enc[k];
        atomicAdd(&w->agg[t], norm * acc2);
        __syncthreads();               // enc reused next iteration
    }
}

// ---- 5. GRU cell on agent row (1x128) and hidden (1x256) -----------------
__global__ void k_gru(const Ws* __restrict__ w,
                      const void* __restrict__ bgcn,
                      const void* __restrict__ hidden,
                      const void* __restrict__ Wih,
                      const void* __restrict__ Whh,
                      const void* __restrict__ bih,
                      const void* __restrict__ bhh,
                      void* __restrict__ out) {
    __shared__ float g0[128];
    __shared__ float h[256];
    int isf32 = w->isf32;
    int t = threadIdx.x;               // 0..255
    if (t < 128) g0[t] = fmaxf(w->agg[t] + ldf(bgcn, isf32, t), 0.0f);
    h[t] = ldf(hidden, isf32, t);
    __syncthreads();

    float gi[3], gh[3];
    for (int p = 0; p < 3; p++) {
        int j = p * 256 + t;
        long long ib = (long long)j * 128;
        float a = ldf(bih, isf32, j);
        for (int k = 0; k < 128; k++) a += ldf(Wih, isf32, ib + k) * g0[k];
        gi[p] = a;
        long long hb = (long long)j * 256;
        float b = ldf(bhh, isf32, j);
        for (int k = 0; k < 256; k++) b += ldf(Whh, isf32, hb + k) * h[k];
        gh[p] = b;
    }
    float r = 1.0f / (1.0f + expf(-(gi[0] + gh[0])));
    float z = 1.0f / (1.0f + expf(-(gi[1] + gh[1])));
    float n = tanhf(gi[2] + r * gh[2]);
    float val = (1.0f - z) * n + z * h[t];
    if (isf32) ((float*)out)[t] = val;
    else       ((bf16*)out)[t] = __float2bfloat16(val);
}

extern "C" void kernel_launch(void* const* d_in, const int* in_sizes, int n_in,
                              void* d_out, int out_size, void* d_ws, size_t ws_size,
                              hipStream_t stream) {
    const void* nf   = d_in[0];
    // d_in[1] edge_attr: unused by the reference
    const void* hid  = d_in[2];
    const void* Wenc = d_in[3];
    const void* benc = d_in[4];
    const void* Wgcn = d_in[5];
    const void* bgcn = d_in[6];
    const void* Wih  = d_in[7];
    const void* Whh  = d_in[8];
    const void* bih  = d_in[9];
    const void* bhh  = d_in[10];
    const void* ei   = d_in[11];
    int E = in_sizes[11] / 2;

    Ws* w = (Ws*)d_ws;

    k_init<<<1, 256, 0, stream>>>(w, ei, Wenc);
    int blocks = (E + 255) / 256;
    k_find<<<blocks, 256, 0, stream>>>(ei, E, w);
    k_deg<<<blocks, 256, 0, stream>>>(ei, E, w);
    k_gather<<<64, 128, 0, stream>>>(nf, Wenc, benc, Wgcn, w);
    k_gru<<<1, 256, 0, stream>>>(w, bgcn, hid, Wih, Whh, bih, bhh, d_out);
}

// Round 3
// 142.342 us; speedup vs baseline: 1.8962x; 1.8962x over previous
//
#include <hip/hip_runtime.h>
#include <hip/hip_bf16.h>

typedef __hip_bfloat16 bf16;

#define CAP 1024   // max tracked edges with dst==0 (expected ~32 = Binomial(E,1/N))

struct Ws {
    int   count;      // number of edges with dst == 0
    int   is64;       // edge_index width: 1 = int64, 0 = int32
    int   isf32;      // float buffers: 1 = fp32, 0 = bf16
    int   pad[13];
    int   srcs[CAP];  // src node of each dst==0 edge
    int   degs[CAP];  // in-degree (excl. self loop) of each listed src
    float agg[128];   // agg row 0 accumulator
    float gi[768];    // GRU input-gate partials
    float gh[768];    // GRU hidden-gate partials
};

// dtype-adaptive float load (wave-uniform branch)
__device__ __forceinline__ float ldf(const void* p, int isf32, long long i) {
    if (isf32) return ((const float*)p)[i];
    return __bfloat162float(((const bf16*)p)[i]);
}

__device__ __forceinline__ int load_idx(const void* ei, int is64, long long pos) {
    if (is64) return (int)((const long long*)ei)[pos];
    return ((const int*)ei)[pos];
}

// ---- 1. init + dtype detection (parallel, one wave) ----------------------
__global__ void k_prep(Ws* w, const void* ei, const void* wenc) {
    int t = threadIdx.x;
    if (t < 64) {
        // Index width: int64 values < 1e5 -> every high 32-bit word is 0.
        int hi = (t < 16) ? ((const int*)ei)[2 * t + 1] : 0;
        unsigned long long any_hi = __ballot(hi != 0);
        // Float width: probe W_enc (values ~N(0,0.05)). Low-mantissa halves of
        // fp32 are uniform random; some have bf16-exponent >= 137 (|v|>=2^10).
        unsigned short u = ((const unsigned short*)wenc)[t];
        unsigned short e = (u >> 7) & 0xFF;
        unsigned long long any_big = __ballot(e >= 137);
        if (t == 0) {
            w->is64  = (any_hi == 0ull) ? 1 : 0;
            w->isf32 = (any_big != 0ull) ? 1 : 0;
            w->count = 0;
        }
    }
    for (int i = t; i < CAP; i += blockDim.x) w->degs[i] = 0;
    for (int i = t; i < 128; i += blockDim.x) w->agg[i] = 0.0f;
}

// ---- 2. find all edges with dst == 0 -------------------------------------
__global__ void k_find(const void* ei, int E, Ws* w) {
    int e = threadIdx.x + blockIdx.x * blockDim.x;
    if (e >= E) return;
    int is64 = w->is64;
    int d = load_idx(ei, is64, (long long)E + e);
    if (d == 0) {
        int p = atomicAdd(&w->count, 1);
        if (p < CAP) w->srcs[p] = load_idx(ei, is64, e);
    }
}

// ---- 3. in-degree of each listed src (small-set histogram) ---------------
__global__ void k_deg(const void* ei, int E, Ws* w) {
    __shared__ int ss[CAP];
    int cnt = min(w->count, CAP);
    for (int i = threadIdx.x; i < cnt; i += blockDim.x) ss[i] = w->srcs[i];
    __syncthreads();
    int e = threadIdx.x + blockIdx.x * blockDim.x;
    if (e >= E) return;
    int d = load_idx(ei, w->is64, (long long)E + e);
    for (int j = 0; j < cnt; j++)
        if (d == ss[j]) atomicAdd(&w->degs[j], 1);
}

// ---- 4. encoder + GCN matvec for the ~33 relevant nodes ------------------
// one block (128 threads) per work item; item i==cnt is the (0,0) self loop
__global__ void k_gather(const void* __restrict__ nf,
                         const void* __restrict__ Wenc,
                         const void* __restrict__ benc,
                         const void* __restrict__ Wgcn,
                         Ws* w) {
    __shared__ float enc[128];
    __shared__ float nrow[64];
    int isf32 = w->isf32;
    int cnt  = min(w->count, CAP);
    int deg0 = w->count + 1;           // self loop included
    int t = threadIdx.x;               // 0..127
    for (int i = blockIdx.x; i <= cnt; i += gridDim.x) {
        int s; float norm;
        if (i < cnt) {
            s = w->srcs[i];
            norm = rsqrtf((float)(w->degs[i] + 1)) * rsqrtf((float)deg0);
        } else {                        // self loop (0,0)
            s = 0;
            norm = 1.0f / (float)deg0;
        }
        if (t < 64) nrow[t] = ldf(nf, isf32, (long long)s * 64 + t);
        __syncthreads();
        // enc[t] = relu(W_enc[t,:] . nf[s,:] + b_enc[t])
        float acc = 0.0f;
        if (isf32) {
            const float4* wr = (const float4*)((const float*)Wenc + (size_t)t * 64);
            #pragma unroll
            for (int k = 0; k < 16; k++) {
                float4 v = wr[k];
                acc += v.x * nrow[4*k] + v.y * nrow[4*k+1]
                     + v.z * nrow[4*k+2] + v.w * nrow[4*k+3];
            }
        } else {
            long long wbase = (long long)t * 64;
            for (int k = 0; k < 64; k++)
                acc += ldf(Wenc, 0, wbase + k) * nrow[k];
        }
        acc += ldf(benc, isf32, t);
        enc[t] = fmaxf(acc, 0.0f);
        __syncthreads();
        // xw[t] = W_gcn[t,:] . enc
        float acc2 = 0.0f;
        if (isf32) {
            const float4* gr = (const float4*)((const float*)Wgcn + (size_t)t * 128);
            #pragma unroll
            for (int k = 0; k < 32; k++) {
                float4 v = gr[k];
                acc2 += v.x * enc[4*k] + v.y * enc[4*k+1]
                      + v.z * enc[4*k+2] + v.w * enc[4*k+3];
            }
        } else {
            long long gbase = (long long)t * 128;
            for (int k = 0; k < 128; k++)
                acc2 += ldf(Wgcn, 0, gbase + k) * enc[k];
        }
        atomicAdd(&w->agg[t], norm * acc2);
        __syncthreads();               // enc/nrow reused next iteration
    }
}

// ---- 5a. GRU matvec partials: one wave per output row j (768 rows) -------
__global__ void k_gru1(Ws* __restrict__ w,
                       const void* __restrict__ bgcn,
                       const void* __restrict__ hidden,
                       const void* __restrict__ Wih,
                       const void* __restrict__ Whh,
                       const void* __restrict__ bih,
                       const void* __restrict__ bhh) {
    int j = blockIdx.x;                // 0..767
    int lane = threadIdx.x;            // 0..63
    int isf32 = w->isf32;

    // ih dot: 128 elems, lane handles k = lane, lane+64
    float a = 0.0f;
    #pragma unroll
    for (int p = 0; p < 2; p++) {
        int k = lane + 64 * p;
        float g0 = fmaxf(w->agg[k] + ldf(bgcn, isf32, k), 0.0f);
        a += ldf(Wih, isf32, (long long)j * 128 + k) * g0;
    }
    // hh dot: 256 elems, lane handles k = 4*lane..4*lane+3
    float b = 0.0f;
    if (isf32) {
        const float4* wr = (const float4*)((const float*)Whh + (size_t)j * 256) + lane;
        const float4* hr = (const float4*)((const float*)hidden) + lane;
        float4 v = *wr, h = *hr;
        b = v.x * h.x + v.y * h.y + v.z * h.z + v.w * h.w;
    } else {
        long long base = (long long)j * 256 + 4 * lane;
        #pragma unroll
        for (int q = 0; q < 4; q++)
            b += ldf(Whh, 0, base + q) * ldf(hidden, 0, 4 * lane + q);
    }
    // wave reduction (64 lanes)
    #pragma unroll
    for (int off = 32; off > 0; off >>= 1) {
        a += __shfl_down(a, off);
        b += __shfl_down(b, off);
    }
    if (lane == 0) {
        w->gi[j] = a + ldf(bih, isf32, j);
        w->gh[j] = b + ldf(bhh, isf32, j);
    }
}

// ---- 5b. GRU gates + output ----------------------------------------------
__global__ void k_gru2(const Ws* __restrict__ w,
                       const void* __restrict__ hidden,
                       void* __restrict__ out) {
    int t = threadIdx.x;               // 0..255
    int isf32 = w->isf32;
    float r = 1.0f / (1.0f + expf(-(w->gi[t]       + w->gh[t])));
    float z = 1.0f / (1.0f + expf(-(w->gi[256 + t] + w->gh[256 + t])));
    float n = tanhf(w->gi[512 + t] + r * w->gh[512 + t]);
    float h = ldf(hidden, isf32, t);
    float val = (1.0f - z) * n + z * h;
    if (isf32) ((float*)out)[t] = val;
    else       ((bf16*)out)[t] = __float2bfloat16(val);
}

extern "C" void kernel_launch(void* const* d_in, const int* in_sizes, int n_in,
                              void* d_out, int out_size, void* d_ws, size_t ws_size,
                              hipStream_t stream) {
    const void* nf   = d_in[0];
    // d_in[1] edge_attr: unused by the reference
    const void* hid  = d_in[2];
    const void* Wenc = d_in[3];
    const void* benc = d_in[4];
    const void* Wgcn = d_in[5];
    const void* bgcn = d_in[6];
    const void* Wih  = d_in[7];
    const void* Whh  = d_in[8];
    const void* bih  = d_in[9];
    const void* bhh  = d_in[10];
    const void* ei   = d_in[11];
    int E = in_sizes[11] / 2;

    Ws* w = (Ws*)d_ws;

    k_prep<<<1, 256, 0, stream>>>(w, ei, Wenc);
    int blocks = (E + 255) / 256;
    k_find<<<blocks, 256, 0, stream>>>(ei, E, w);
    k_deg<<<blocks, 256, 0, stream>>>(ei, E, w);
    k_gather<<<64, 128, 0, stream>>>(nf, Wenc, benc, Wgcn, w);
    k_gru1<<<768, 64, 0, stream>>>(w, bgcn, hid, Wih, Whh, bih, bhh);
    k_gru2<<<1, 256, 0, stream>>>(w, hid, d_out);
}